// Round 8
// baseline (567.120 us; speedup 1.0000x reference)
//
#include <hip/hip_runtime.h>
#include <hip/hip_bf16.h>

#define NNODES 32768
#define NEDGES 524288
#define NGRAPH 512
#define PNODES 64
#define KTOP 30
#define FIN 128
#define HID 256
#define LOUT 27

#define C1F 4.8828125e-4f           // 2^-11
#define C2F 2.384185791015625e-7f   // 2^-22

using f16x8 = __attribute__((ext_vector_type(8))) _Float16;
using f16x4 = __attribute__((ext_vector_type(4))) _Float16;
using f32x4 = __attribute__((ext_vector_type(4))) float;
using f32x16 = __attribute__((ext_vector_type(16))) float;

// ---------- edge preprocessing ----------
__global__ void hist_kernel(const int* __restrict__ dst, int* __restrict__ counts) {
    int e = blockIdx.x * blockDim.x + threadIdx.x;
    if (e < NEDGES) atomicAdd(&counts[dst[e]], 1);
}

__global__ __launch_bounds__(1024) void scan_block_kernel(const int* __restrict__ counts,
        int* __restrict__ loc, int* __restrict__ partial) {
    int b = blockIdx.x, t = threadIdx.x;
    int i = b * 1024 + t;
    int v = counts[i];
    int lane = t & 63, w = t >> 6;
    int x = v;
    #pragma unroll
    for (int d = 1; d < 64; d <<= 1) { int y = __shfl_up(x, d, 64); if (lane >= d) x += y; }
    __shared__ int ws[16];
    if (lane == 63) ws[w] = x;
    __syncthreads();
    if (w == 0) {
        int s = (lane < 16) ? ws[lane] : 0;
        #pragma unroll
        for (int d = 1; d < 16; d <<= 1) { int y = __shfl_up(s, d, 64); if (lane >= d) s += y; }
        if (lane < 16) ws[lane] = s;
    }
    __syncthreads();
    int base = (w > 0) ? ws[w - 1] : 0;
    int incl = base + x;
    loc[i] = incl - v;
    if (t == 1023) partial[b] = incl;
}

__global__ __launch_bounds__(1024) void scan_fixup_kernel(const int* __restrict__ loc,
        const int* __restrict__ partial, const int* __restrict__ counts,
        int* __restrict__ offsets, int* __restrict__ cursor, float* __restrict__ invdeg) {
    int b = blockIdx.x, t = threadIdx.x;
    int i = b * 1024 + t;
    __shared__ int sbase;
    if (t == 0) { int s = 0; for (int j = 0; j < b; ++j) s += partial[j]; sbase = s; }
    __syncthreads();
    int o = loc[i] + sbase;
    offsets[i] = o;
    cursor[i] = o;
    invdeg[i] = 1.0f / fmaxf((float)counts[i], 1.0f);
}

__global__ void scatter_kernel(const int* __restrict__ src, const int* __restrict__ dst,
        int* __restrict__ cursor, int* __restrict__ ssrc) {
    int e = blockIdx.x * blockDim.x + threadIdx.x;
    if (e < NEDGES) {
        int d = dst[e];
        int p = atomicAdd(&cursor[d], 1);
        ssrc[p] = src[e];
    }
}

// nan_to_num + split to f16 pair
__global__ void nan2num_split_kernel(const float* __restrict__ x,
        _Float16* __restrict__ oh, _Float16* __restrict__ ol, int n4) {
    int i = blockIdx.x * blockDim.x + threadIdx.x;
    if (i >= n4) return;
    float4 v = *(const float4*)(x + i * 4);
    float xs[4] = {v.x, v.y, v.z, v.w};
    f16x4 hh, ll;
    #pragma unroll
    for (int q = 0; q < 4; ++q) {
        float a = xs[q];
        a = (a != a) ? 0.f : a;
        _Float16 h = (_Float16)a;
        hh[q] = h;
        ll[q] = (_Float16)((a - (float)h) * 2048.0f);
    }
    *(f16x4*)(oh + (size_t)i * 4) = hh;
    *(f16x4*)(ol + (size_t)i * 4) = ll;
}

// ---------- weight prep ----------
struct Prep8 {
    const float* src[8];
    _Float16* dh[8];
    _Float16* dl[8];
    int logK[8];
    int nelem[8];
};

// W [K][256] f32 -> [256][K] f16 split (8 weights in one launch)
__global__ __launch_bounds__(256) void prep8_kernel(Prep8 p) {
    int y = blockIdx.y;
    int idx = blockIdx.x * 256 + threadIdx.x;
    if (idx >= p.nelem[y]) return;
    int lk = p.logK[y], K = 1 << lk;
    int n = idx >> lk, k = idx & (K - 1);
    float w = p.src[y][(size_t)k * 256 + n];
    _Float16 h = (_Float16)w;
    p.dh[y][(size_t)n * K + k] = h;
    p.dl[y][(size_t)n * K + k] = (_Float16)((w - (float)h) * 2048.0f);
}

// conv1d weight (o, i, t) -> [o][k=t*256+i] split
__global__ __launch_bounds__(256) void prep_conv_kernel(const float* __restrict__ W,
        _Float16* __restrict__ b0, _Float16* __restrict__ b1) {
    int idx = blockIdx.x * 256 + threadIdx.x;  // over 256*1024
    int o = idx >> 10, k = idx & 1023;
    float w = W[(size_t)o * 1024 + (k & 255) * 4 + (k >> 8)];
    _Float16 h = (_Float16)w;
    b0[(size_t)o * 1024 + k] = h;
    b1[(size_t)o * 1024 + k] = (_Float16)((w - (float)h) * 2048.0f);
}

// lin1_w [(c*27+l)][n] -> out [n][k=l*256+c] f16 split, via LDS transpose
__global__ __launch_bounds__(256) void prep_lin1_kernel(const float* __restrict__ l1w,
        _Float16* __restrict__ wh, _Float16* __restrict__ wl_) {
    __shared__ float sh[64][65];
    int kb = blockIdx.x * 64;   // 108 tiles over k
    int nb = blockIdx.y * 64;   // 4 tiles over n
    int t = threadIdx.x;
    {
        int kk = t >> 2;
        int nc = (t & 3) * 16;
        int k = kb + kk, l = k >> 8, c = k & 255;
        const float* srow = l1w + (size_t)(c * 27 + l) * 256 + nb + nc;
        #pragma unroll
        for (int j = 0; j < 16; j += 4) {
            float4 v = *(const float4*)(srow + j);
            sh[kk][nc + j + 0] = v.x;
            sh[kk][nc + j + 1] = v.y;
            sh[kk][nc + j + 2] = v.z;
            sh[kk][nc + j + 3] = v.w;
        }
    }
    __syncthreads();
    {
        int nn = t >> 2;
        int kc = (t & 3) * 16;
        f16x8 oh[2], ol[2];
        #pragma unroll
        for (int j = 0; j < 16; ++j) {
            float x = sh[kc + j][nn];
            _Float16 h = (_Float16)x;
            oh[j >> 3][j & 7] = h;
            ol[j >> 3][j & 7] = (_Float16)((x - (float)h) * 2048.0f);
        }
        size_t o = (size_t)(nb + nn) * 6912 + kb + kc;
        *(f16x8*)(wh + o) = oh[0];
        *(f16x8*)(wh + o + 8) = oh[1];
        *(f16x8*)(wl_ + o) = ol[0];
        *(f16x8*)(wl_ + o + 8) = ol[1];
    }
}

// ---------- per-graph LDS-staged mean aggregation (split IO) ----------
template<int H, int LOGH>
__global__ __launch_bounds__(256) void aggregate_ps_kernel(
        const _Float16* __restrict__ hh, const _Float16* __restrict__ hl,
        const int* __restrict__ offsets, const int* __restrict__ counts,
        const int* __restrict__ ssrc, const float* __restrict__ invdeg,
        _Float16* __restrict__ aggh, _Float16* __restrict__ aggl) {
    __shared__ float sh[64 * H];
    const int g = blockIdx.x, t = threadIdx.x;
    const size_t base = (size_t)g * 64 * H;
    for (int i4 = t * 4; i4 < 64 * H; i4 += 1024) {
        f16x4 vh = *(const f16x4*)(hh + base + i4);
        f16x4 vl = *(const f16x4*)(hl + base + i4);
        int row = i4 >> LOGH, col = i4 & (H - 1);
        int sw = row & 30;
        float x0 = (float)vh[0] + C1F * (float)vl[0];
        float x1 = (float)vh[1] + C1F * (float)vl[1];
        float x2 = (float)vh[2] + C1F * (float)vl[2];
        float x3 = (float)vh[3] + C1F * (float)vl[3];
        *(float2*)&sh[(row << LOGH) + (col ^ sw)] = make_float2(x0, x1);
        *(float2*)&sh[(row << LOGH) + ((col + 2) ^ sw)] = make_float2(x2, x3);
    }
    __syncthreads();
    const int n = t >> 2, fb = t & 3;
    const int FQ = H >> 2;
    const int node = g * 64 + n;
    const int beg = offsets[node], cnt = counts[node];
    float acc[FQ];
    #pragma unroll
    for (int j = 0; j < FQ; ++j) acc[j] = 0.f;
    for (int e = 0; e < cnt; ++e) {
        int sn = ssrc[beg + e] & 63;
        int rowoff = sn << LOGH;
        int sw = sn & 30;
        #pragma unroll
        for (int j = 0; j < FQ; j += 2) {
            int f = fb * FQ + (j ^ (fb * 8));
            float2 v = *(float2*)&sh[rowoff + (f ^ sw)];
            acc[j]     += v.x;
            acc[j + 1] += v.y;
        }
    }
    float s = invdeg[node];
    __syncthreads();
    {
        int rowoff = n << LOGH;
        int sw = n & 30;
        #pragma unroll
        for (int j = 0; j < FQ; j += 2) {
            int f = fb * FQ + (j ^ (fb * 8));
            *(float2*)&sh[rowoff + (f ^ sw)] = make_float2(acc[j] * s, acc[j + 1] * s);
        }
    }
    __syncthreads();
    for (int i4 = t * 4; i4 < 64 * H; i4 += 1024) {
        int row = i4 >> LOGH, col = i4 & (H - 1);
        int sw = row & 30;
        float2 a = *(float2*)&sh[(row << LOGH) + (col ^ sw)];
        float2 b = *(float2*)&sh[(row << LOGH) + ((col + 2) ^ sw)];
        float xs[4] = {a.x, a.y, b.x, b.y};
        f16x4 oh, ol;
        #pragma unroll
        for (int q = 0; q < 4; ++q) {
            _Float16 h = (_Float16)xs[q];
            oh[q] = h;
            ol[q] = (_Float16)((xs[q] - (float)h) * 2048.0f);
        }
        *(f16x4*)(aggh + base + i4) = oh;
        *(f16x4*)(aggl + base + i4) = ol;
    }
}

// ---------- pre-split MFMA GEMM: 128x128 block, 32x32x16 fragments ----------
// Wave tile 64x64 = 2x2 of mfma_f32_32x32x16_f16 -> 8KB fragment reads per wave
// per k32 (half of the 16x16x32 layout). LDS rows stride 20 f16 -> 2-way bank
// aliasing only (free). acc0: a0b0 (x1); acc1: a1b0+a0b1 (x2^-11); acc2: a1b1
// (x2^-22, NPROD==4). 1D grid: rb=bid%nrb (XCD swizzle), cb=bid/nrb.
// EPI 0: bias+relu, split f16 store. EPI 1: f32 partial at Cpart[z][row][col].
// EPI 2: atomicAdd into Cpart[row][col].
template<int NPROD, int CONV, int NPAIRS, int EPI>
__global__ __launch_bounds__(256, 2) void mfma_ps_kernel(
        const _Float16* __restrict__ A1h, const _Float16* __restrict__ A1l,
        const _Float16* __restrict__ A2h, const _Float16* __restrict__ A2l,
        const _Float16* __restrict__ B1h, const _Float16* __restrict__ B1l,
        const _Float16* __restrict__ B2h, const _Float16* __restrict__ B2l,
        const float* __restrict__ bias,
        _Float16* __restrict__ outh, _Float16* __restrict__ outl,
        float* __restrict__ Cpart,
        int lda, int K, int Nd, int nrb) {
    // [term][k16-half][row*20 + k]
    __shared__ _Float16 As[2][2][128 * 20];
    __shared__ _Float16 Bs[2][2][128 * 20];
    const int t = threadIdx.x;
    const int lane = t & 63, wave = t >> 6;
    const int wr = wave & 1, wc = wave >> 1;
    const int bid = blockIdx.x;
    const int rb = bid % nrb, cb = bid / nrb;
    const int row0 = rb * 128, col0 = cb * 128;
    const int l31 = lane & 31, kh8 = (lane >> 5) * 8;
    const int srow = t >> 1, shalf = t & 1;     // staging: 128 rows x 2 k16-halves
    const int kchunk = K / gridDim.z;
    const int k_lo = blockIdx.z * kchunk, k_hi = k_lo + kchunk;

    f32x16 acc0[2][2], acc1[2][2], acc2[2][2];
    #pragma unroll
    for (int i = 0; i < 2; ++i)
        #pragma unroll
        for (int j = 0; j < 2; ++j) { acc0[i][j] = 0.f; acc1[i][j] = 0.f; acc2[i][j] = 0.f; }

    #pragma unroll
    for (int p = 0; p < NPAIRS; ++p) {
        const _Float16* __restrict__ Ah = p ? A2h : A1h;
        const _Float16* __restrict__ Al = p ? A2l : A1l;
        const _Float16* __restrict__ Bh = p ? B2h : B1h;
        const _Float16* __restrict__ Bl = p ? B2l : B1l;
        const int ar = row0 + srow;
        const size_t aoff = (CONV ? ((size_t)ar * 256 + (size_t)(ar / 27) * 768)
                                  : (size_t)ar * (size_t)lda) + shalf * 16;
        const size_t boff = (size_t)(col0 + srow) * (size_t)K + shalf * 16;
        const int sdst = srow * 20;
        for (int k0 = k_lo; k0 < k_hi; k0 += 32) {
            f16x8 a0a = *(const f16x8*)(Ah + aoff + k0);
            f16x8 a0b = *(const f16x8*)(Ah + aoff + k0 + 8);
            f16x8 a1a = *(const f16x8*)(Al + aoff + k0);
            f16x8 a1b = *(const f16x8*)(Al + aoff + k0 + 8);
            f16x8 b0a = *(const f16x8*)(Bh + boff + k0);
            f16x8 b0b = *(const f16x8*)(Bh + boff + k0 + 8);
            f16x8 b1a = *(const f16x8*)(Bl + boff + k0);
            f16x8 b1b = *(const f16x8*)(Bl + boff + k0 + 8);
            __syncthreads();   // previous iter's LDS reads complete
            *(f16x8*)&As[0][shalf][sdst]     = a0a;
            *(f16x8*)&As[0][shalf][sdst + 8] = a0b;
            *(f16x8*)&As[1][shalf][sdst]     = a1a;
            *(f16x8*)&As[1][shalf][sdst + 8] = a1b;
            *(f16x8*)&Bs[0][shalf][sdst]     = b0a;
            *(f16x8*)&Bs[0][shalf][sdst + 8] = b0b;
            *(f16x8*)&Bs[1][shalf][sdst]     = b1a;
            *(f16x8*)&Bs[1][shalf][sdst + 8] = b1b;
            __syncthreads();
            #pragma unroll
            for (int half = 0; half < 2; ++half) {
                f16x8 af0[2], af1[2], bf0[2], bf1[2];
                #pragma unroll
                for (int mi = 0; mi < 2; ++mi) {
                    int mrow = wr * 64 + mi * 32 + l31;
                    af0[mi] = *(f16x8*)&As[0][half][mrow * 20 + kh8];
                    af1[mi] = *(f16x8*)&As[1][half][mrow * 20 + kh8];
                }
                #pragma unroll
                for (int ni = 0; ni < 2; ++ni) {
                    int nrow = wc * 64 + ni * 32 + l31;
                    bf0[ni] = *(f16x8*)&Bs[0][half][nrow * 20 + kh8];
                    bf1[ni] = *(f16x8*)&Bs[1][half][nrow * 20 + kh8];
                }
                #pragma unroll
                for (int mi = 0; mi < 2; ++mi)
                    #pragma unroll
                    for (int ni = 0; ni < 2; ++ni) {
                        acc0[mi][ni] = __builtin_amdgcn_mfma_f32_32x32x16_f16(af0[mi], bf0[ni], acc0[mi][ni], 0, 0, 0);
                        acc1[mi][ni] = __builtin_amdgcn_mfma_f32_32x32x16_f16(af1[mi], bf0[ni], acc1[mi][ni], 0, 0, 0);
                        acc1[mi][ni] = __builtin_amdgcn_mfma_f32_32x32x16_f16(af0[mi], bf1[ni], acc1[mi][ni], 0, 0, 0);
                        if (NPROD == 4)
                            acc2[mi][ni] = __builtin_amdgcn_mfma_f32_32x32x16_f16(af1[mi], bf1[ni], acc2[mi][ni], 0, 0, 0);
                    }
            }
        }
    }
    // C/D: col = lane&31, row = (reg&3) + 8*(reg>>2) + 4*(lane>>5)  [m74/m101]
    const int rquad = 4 * (lane >> 5);
    #pragma unroll
    for (int ni = 0; ni < 2; ++ni) {
        int col = col0 + wc * 64 + ni * 32 + l31;
        float bb = (EPI == 0) ? bias[col] : 0.f;
        #pragma unroll
        for (int mi = 0; mi < 2; ++mi) {
            #pragma unroll
            for (int reg = 0; reg < 16; ++reg) {
                float v = acc0[mi][ni][reg] + C1F * acc1[mi][ni][reg];
                if (NPROD == 4) v += C2F * acc2[mi][ni][reg];
                int row = row0 + wr * 64 + mi * 32 + (reg & 3) + 8 * (reg >> 2) + rquad;
                if (EPI == 0) {
                    v = fmaxf(v + bb, 0.f);
                    _Float16 h = (_Float16)v;
                    size_t o = (size_t)row * Nd + col;
                    outh[o] = h;
                    outl[o] = (_Float16)((v - (float)h) * 2048.0f);
                } else if (EPI == 1) {
                    size_t zb = (size_t)blockIdx.z * (size_t)(nrb * 128) * Nd;
                    Cpart[zb + (size_t)row * Nd + col] = v;
                } else {
                    atomicAdd(&Cpart[(size_t)row * Nd + col], v);
                }
            }
        }
    }
}

// ---------- fused sort-pool + top-k gather ----------
__global__ __launch_bounds__(256) void sortgather_kernel(const _Float16* __restrict__ hh,
        const _Float16* __restrict__ hl, _Float16* __restrict__ th, _Float16* __restrict__ tl) {
    __shared__ float vals[PNODES];
    __shared__ int ord[KTOP];
    int g = blockIdx.x, t = threadIdx.x;
    if (t < PNODES) {
        size_t idx = (size_t)(g * PNODES + t) * HID + (HID - 1);
        vals[t] = (float)hh[idx] + C1F * (float)hl[idx];
    }
    __syncthreads();
    if (t < PNODES) {
        float v = vals[t];
        int rank = 0;
        for (int j = 0; j < PNODES; ++j) {
            float vj = vals[j];
            rank += (vj > v) || (vj == v && j < t);
        }
        if (rank < KTOP) ord[rank] = g * PNODES + t;
    }
    __syncthreads();
    for (int r = 0; r < KTOP; ++r) {
        size_t s = (size_t)ord[r] * HID + t;
        size_t d = (size_t)(g * KTOP + r) * HID + t;
        th[d] = hh[s];
        tl[d] = hl[s];
    }
}

// ---------- conv reduce: bias+relu+split ----------
__global__ void reduce_conv_kernel(const float* __restrict__ yb32,
        const float* __restrict__ b, _Float16* __restrict__ ybh, _Float16* __restrict__ ybl) {
    int i = blockIdx.x * 256 + threadIdx.x;   // over 13824*256
    float v = fmaxf(yb32[i] + b[i & 255], 0.f);
    _Float16 h = (_Float16)v;
    ybh[i] = h;
    ybl[i] = (_Float16)((v - (float)h) * 2048.0f);
}

// ---------- lin1 reduce (27 partials) ----------
__global__ void reduce_lin1_kernel(const float* __restrict__ z1p,
        const float* __restrict__ b, float* __restrict__ z1) {
    int i = blockIdx.x * 256 + threadIdx.x;   // 131072
    float s = b[i & 255];
    #pragma unroll
    for (int z = 0; z < 27; ++z) s += z1p[(size_t)z * 131072 + i];
    z1[i] = fmaxf(s, 0.f);
}

// ---------- f32 64x64 GEMM (lin2 only) ----------
__global__ __launch_bounds__(256) void gemm64_kernel(
        const float* __restrict__ A, const float* __restrict__ B,
        const float* __restrict__ bias, float* __restrict__ C,
        int lda, int kend, int Nd) {
    __shared__ float As[16][64];
    __shared__ float Bs[16][64];
    const int tid = threadIdx.x;
    const int tx = tid & 15, ty = tid >> 4;
    const int la_r = tid >> 2, la_c = (tid & 3) << 2;
    const int lb_r = tid >> 4, lb_c = (tid & 15) << 2;
    const int row0 = blockIdx.x * 64, col0 = blockIdx.y * 64;
    const size_t aoff = (size_t)(row0 + la_r) * (size_t)lda;
    float acc[4][4] = {};
    for (int k0 = 0; k0 < kend; k0 += 16) {
        __syncthreads();
        float4 av = *(const float4*)(A + aoff + k0 + la_c);
        As[la_c + 0][la_r] = av.x;
        As[la_c + 1][la_r] = av.y;
        As[la_c + 2][la_r] = av.z;
        As[la_c + 3][la_r] = av.w;
        *(float4*)&Bs[lb_r][lb_c] = *(const float4*)(B + (size_t)(k0 + lb_r) * Nd + col0 + lb_c);
        __syncthreads();
        #pragma unroll
        for (int k = 0; k < 16; ++k) {
            float4 a = *(const float4*)&As[k][ty << 2];
            float4 b = *(const float4*)&Bs[k][tx << 2];
            acc[0][0] += a.x * b.x; acc[0][1] += a.x * b.y; acc[0][2] += a.x * b.z; acc[0][3] += a.x * b.w;
            acc[1][0] += a.y * b.x; acc[1][1] += a.y * b.y; acc[1][2] += a.y * b.z; acc[1][3] += a.y * b.w;
            acc[2][0] += a.z * b.x; acc[2][1] += a.z * b.y; acc[2][2] += a.z * b.z; acc[2][3] += a.z * b.w;
            acc[3][0] += a.w * b.x; acc[3][1] += a.w * b.y; acc[3][2] += a.w * b.z; acc[3][3] += a.w * b.w;
        }
    }
    #pragma unroll
    for (int i = 0; i < 4; ++i) {
        int row = row0 + (ty << 2) + i;
        #pragma unroll
        for (int j = 0; j < 4; ++j) {
            int col = col0 + (tx << 2) + j;
            C[(size_t)row * Nd + col] = fmaxf(acc[i][j] + bias[col], 0.f);
        }
    }
}

__global__ void out_kernel(const float* __restrict__ z2, const float* __restrict__ w,
        const float* __restrict__ b, float* __restrict__ out) {
    int idx = blockIdx.x * blockDim.x + threadIdx.x;
    if (idx < NGRAPH * 10) {
        int r = idx / 10, c = idx % 10;
        float s = b[c];
        for (int k = 0; k < 128; ++k) s += z2[r * 128 + k] * w[k * 10 + c];
        out[idx] = fmaxf(s, 0.f);
    }
}

extern "C" void kernel_launch(void* const* d_in, const int* in_sizes, int n_in,
                              void* d_out, int out_size, void* d_ws, size_t ws_size,
                              hipStream_t stream) {
    const float* x    = (const float*)d_in[0];
    const int*   edge = (const int*)d_in[1];
    const int*   esrc = edge;
    const int*   edst = edge + NEDGES;
    const float* wl[4] = {(const float*)d_in[3], (const float*)d_in[6], (const float*)d_in[9],  (const float*)d_in[12]};
    const float* wr[4] = {(const float*)d_in[4], (const float*)d_in[7], (const float*)d_in[10], (const float*)d_in[13]};
    const float* sb[4] = {(const float*)d_in[5], (const float*)d_in[8], (const float*)d_in[11], (const float*)d_in[14]};
    const float* convw = (const float*)d_in[15];
    const float* convb = (const float*)d_in[16];
    const float* l1w   = (const float*)d_in[17];
    const float* l1b   = (const float*)d_in[18];
    const float* l2w   = (const float*)d_in[19];
    const float* l2b   = (const float*)d_in[20];
    const float* ow    = (const float*)d_in[21];
    const float* ob    = (const float*)d_in[22];
    float* out = (float*)d_out;

    char* ws = (char*)d_ws;
    size_t off = 0;
    auto alloc = [&](size_t bytes) -> char* {
        char* p = ws + off;
        off = (off + bytes + 255) & ~(size_t)255;
        return p;
    };
    int*   counts  = (int*)alloc((size_t)NNODES * 4);
    int*   offsets = (int*)alloc((size_t)NNODES * 4);
    int*   cursor  = (int*)alloc((size_t)NNODES * 4);
    int*   loc     = (int*)alloc((size_t)NNODES * 4);
    int*   partial = (int*)alloc(32 * 4);
    float* invdeg  = (float*)alloc((size_t)NNODES * 4);
    int*   ssrc    = (int*)alloc((size_t)NEDGES * 4);
    _Float16* wlh[4]; _Float16* wll[4]; _Float16* wrh[4]; _Float16* wrl[4];
    for (int l = 0; l < 4; ++l) {
        size_t kb = (size_t)(l ? HID : FIN) * HID * 2;
        wlh[l] = (_Float16*)alloc(kb); wll[l] = (_Float16*)alloc(kb);
        wrh[l] = (_Float16*)alloc(kb); wrl[l] = (_Float16*)alloc(kb);
    }
    _Float16* cvh = (_Float16*)alloc((size_t)HID * 1024 * 2);
    _Float16* cvl = (_Float16*)alloc((size_t)HID * 1024 * 2);

    const size_t H0T = (size_t)NNODES * FIN * 2;        // 8.39 MB
    const size_t AGT = (size_t)NNODES * HID * 2;        // 16.78 MB
    const size_t TKT = (size_t)NGRAPH * KTOP * HID * 2; // 7.86 MB
    const size_t YBT = (size_t)NGRAPH * LOUT * HID * 2; // 7.08 MB
    const size_t Z1PT = (size_t)27 * NGRAPH * HID * 4;  // 14.16 MB (= conv f32 buf size)
    const size_t W1T = (size_t)HID * 6912 * 2;          // 3.54 MB

    char* R1 = alloc(2 * H0T);
    char* R2 = alloc(2 * AGT);
    char* R3 = alloc(2 * AGT);
    char* R4 = alloc(2 * AGT);
    // region 1: h0 split (SAGE phase) -> topk split (tail phase)
    _Float16* h0h = (_Float16*)R1; _Float16* h0l = (_Float16*)(R1 + H0T);
    _Float16* tkh = (_Float16*)R1; _Float16* tkl = (_Float16*)(R1 + TKT);
    // region 2: agg split -> ybl split + (conv f32 accum / z1p union) + z1 + z2
    _Float16* aggh = (_Float16*)R2; _Float16* aggl = (_Float16*)(R2 + AGT);
    _Float16* ybh = (_Float16*)R2; _Float16* ybl_ = (_Float16*)(R2 + YBT);
    float* yb32 = (float*)(R2 + 2 * YBT);               // 13824*256*4 = 14.16 MB
    float* z1p  = (float*)(R2 + 2 * YBT);               // union (yb32 dead before lin1)
    float* z1  = (float*)(R2 + 2 * YBT + Z1PT);
    float* z2  = (float*)(R2 + 2 * YBT + Z1PT + (size_t)NGRAPH * HID * 4);
    // region 3: hA split -> lin1 weight split
    _Float16* hAh = (_Float16*)R3; _Float16* hAl = (_Float16*)(R3 + AGT);
    _Float16* w1h = (_Float16*)R3; _Float16* w1l = (_Float16*)(R3 + W1T);
    // region 4: hB split (= h4, live to end)
    _Float16* hBh = (_Float16*)R4; _Float16* hBl = (_Float16*)(R4 + AGT);

    // ---- edge prep ----
    hipMemsetAsync(counts, 0, (size_t)NNODES * 4, stream);
    hist_kernel<<<NEDGES / 256, 256, 0, stream>>>(edst, counts);
    scan_block_kernel<<<NNODES / 1024, 1024, 0, stream>>>(counts, loc, partial);
    scan_fixup_kernel<<<NNODES / 1024, 1024, 0, stream>>>(loc, partial, counts, offsets, cursor, invdeg);
    scatter_kernel<<<NEDGES / 256, 256, 0, stream>>>(esrc, edst, cursor, ssrc);
    nan2num_split_kernel<<<(NNODES * FIN / 4) / 256, 256, 0, stream>>>(x, h0h, h0l, NNODES * FIN / 4);

    // ---- weight prep ----
    Prep8 p8;
    for (int l = 0; l < 4; ++l) {
        int K = l ? HID : FIN, lk = l ? 8 : 7;
        p8.src[2 * l] = wl[l];     p8.dh[2 * l] = wlh[l];     p8.dl[2 * l] = wll[l];
        p8.src[2 * l + 1] = wr[l]; p8.dh[2 * l + 1] = wrh[l]; p8.dl[2 * l + 1] = wrl[l];
        p8.logK[2 * l] = lk;   p8.nelem[2 * l] = 256 * K;
        p8.logK[2 * l + 1] = lk; p8.nelem[2 * l + 1] = 256 * K;
    }
    prep8_kernel<<<dim3(256, 8), 256, 0, stream>>>(p8);
    prep_conv_kernel<<<(HID * 1024) / 256, 256, 0, stream>>>(convw, cvh, cvl);

    // ---- layer 0 (K=128) ----
    aggregate_ps_kernel<FIN, 7><<<NGRAPH, 256, 0, stream>>>(h0h, h0l, offsets, counts, ssrc, invdeg, aggh, aggl);
    mfma_ps_kernel<4, 0, 2, 0><<<dim3(256 * 2, 1, 1), 256, 0, stream>>>(
        aggh, aggl, h0h, h0l, wlh[0], wll[0], wrh[0], wrl[0], sb[0], hAh, hAl, nullptr, FIN, FIN, HID, 256);
    // ---- layers 1..3 (K=256) ----
    _Float16* hinh = hAh; _Float16* hinl = hAl;
    _Float16* hoth = hBh; _Float16* hotl = hBl;
    for (int l = 1; l < 4; ++l) {
        aggregate_ps_kernel<HID, 8><<<NGRAPH, 256, 0, stream>>>(hinh, hinl, offsets, counts, ssrc, invdeg, aggh, aggl);
        mfma_ps_kernel<4, 0, 2, 0><<<dim3(256 * 2, 1, 1), 256, 0, stream>>>(
            aggh, aggl, hinh, hinl, wlh[l], wll[l], wrh[l], wrl[l], sb[l], hoth, hotl, nullptr, HID, HID, HID, 256);
        _Float16* t1 = hinh; hinh = hoth; hoth = t1;
        _Float16* t2 = hinl; hinl = hotl; hotl = t2;
    }
    // h4 = (hinh, hinl) = hB region

    sortgather_kernel<<<NGRAPH, 256, 0, stream>>>(hinh, hinl, tkh, tkl);
    prep_lin1_kernel<<<dim3(108, 4), 256, 0, stream>>>(l1w, w1h, w1l);

    // ---- conv1d as GEMM: M=13824, K=1024, split-K=2 via f32 atomics ----
    hipMemsetAsync(yb32, 0, (size_t)13824 * 256 * 4, stream);
    mfma_ps_kernel<3, 1, 1, 2><<<dim3(108 * 2, 1, 2), 256, 0, stream>>>(
        tkh, tkl, nullptr, nullptr, cvh, cvl, nullptr, nullptr, nullptr, nullptr, nullptr, yb32, 256, 1024, HID, 108);
    reduce_conv_kernel<<<13824 * 256 / 256, 256, 0, stream>>>(yb32, convb, ybh, ybl_);

    // ---- lin1: M=512, K=6912, split-K=27 partials + reduce ----
    mfma_ps_kernel<3, 0, 1, 1><<<dim3(4 * 2, 1, 27), 256, 0, stream>>>(
        ybh, ybl_, nullptr, nullptr, w1h, w1l, nullptr, nullptr, nullptr, nullptr, nullptr, z1p, 6912, 6912, HID, 4);
    reduce_lin1_kernel<<<NGRAPH * HID / 256, 256, 0, stream>>>(z1p, l1b, z1);

    // ---- lin2: M=512, K=256, N=128 ----
    gemm64_kernel<<<dim3(NGRAPH / 64, 128 / 64), 256, 0, stream>>>(z1, l2w, l2b, z2, HID, HID, 128);

    // ---- out ----
    out_kernel<<<(NGRAPH * 10 + 255) / 256, 256, 0, stream>>>(z2, ow, ob, out);
}

// Round 9
// 532.647 us; speedup vs baseline: 1.0647x; 1.0647x over previous
//
#include <hip/hip_runtime.h>
#include <hip/hip_bf16.h>

#define NNODES 32768
#define NEDGES 524288
#define NGRAPH 512
#define PNODES 64
#define KTOP 30
#define FIN 128
#define HID 256
#define LOUT 27

#define C1F 4.8828125e-4f           // 2^-11
#define C2F 2.384185791015625e-7f   // 2^-22

using f16x8 = __attribute__((ext_vector_type(8))) _Float16;
using f16x4 = __attribute__((ext_vector_type(4))) _Float16;
using f32x4 = __attribute__((ext_vector_type(4))) float;
using f32x16 = __attribute__((ext_vector_type(16))) float;

// async global->LDS DMA, 16B per lane, dest = wave-uniform base + lane*16
#define GLDS(src, dst) __builtin_amdgcn_global_load_lds( \
    (const __attribute__((address_space(1))) void*)(src), \
    (__attribute__((address_space(3))) void*)(dst), 16, 0, 0)

// ---------- edge preprocessing ----------
__global__ void hist_kernel(const int* __restrict__ dst, int* __restrict__ counts) {
    int e = blockIdx.x * blockDim.x + threadIdx.x;
    if (e < NEDGES) atomicAdd(&counts[dst[e]], 1);
}

__global__ __launch_bounds__(1024) void scan_block_kernel(const int* __restrict__ counts,
        int* __restrict__ loc, int* __restrict__ partial) {
    int b = blockIdx.x, t = threadIdx.x;
    int i = b * 1024 + t;
    int v = counts[i];
    int lane = t & 63, w = t >> 6;
    int x = v;
    #pragma unroll
    for (int d = 1; d < 64; d <<= 1) { int y = __shfl_up(x, d, 64); if (lane >= d) x += y; }
    __shared__ int ws[16];
    if (lane == 63) ws[w] = x;
    __syncthreads();
    if (w == 0) {
        int s = (lane < 16) ? ws[lane] : 0;
        #pragma unroll
        for (int d = 1; d < 16; d <<= 1) { int y = __shfl_up(s, d, 64); if (lane >= d) s += y; }
        if (lane < 16) ws[lane] = s;
    }
    __syncthreads();
    int base = (w > 0) ? ws[w - 1] : 0;
    int incl = base + x;
    loc[i] = incl - v;
    if (t == 1023) partial[b] = incl;
}

__global__ __launch_bounds__(1024) void scan_fixup_kernel(const int* __restrict__ loc,
        const int* __restrict__ partial, const int* __restrict__ counts,
        int* __restrict__ offsets, int* __restrict__ cursor, float* __restrict__ invdeg) {
    int b = blockIdx.x, t = threadIdx.x;
    int i = b * 1024 + t;
    __shared__ int sbase;
    if (t == 0) { int s = 0; for (int j = 0; j < b; ++j) s += partial[j]; sbase = s; }
    __syncthreads();
    int o = loc[i] + sbase;
    offsets[i] = o;
    cursor[i] = o;
    invdeg[i] = 1.0f / fmaxf((float)counts[i], 1.0f);
}

__global__ void scatter_kernel(const int* __restrict__ src, const int* __restrict__ dst,
        int* __restrict__ cursor, int* __restrict__ ssrc) {
    int e = blockIdx.x * blockDim.x + threadIdx.x;
    if (e < NEDGES) {
        int d = dst[e];
        int p = atomicAdd(&cursor[d], 1);
        ssrc[p] = src[e];
    }
}

// nan_to_num + split to f16 pair
__global__ void nan2num_split_kernel(const float* __restrict__ x,
        _Float16* __restrict__ oh, _Float16* __restrict__ ol, int n4) {
    int i = blockIdx.x * blockDim.x + threadIdx.x;
    if (i >= n4) return;
    float4 v = *(const float4*)(x + i * 4);
    float xs[4] = {v.x, v.y, v.z, v.w};
    f16x4 hh, ll;
    #pragma unroll
    for (int q = 0; q < 4; ++q) {
        float a = xs[q];
        a = (a != a) ? 0.f : a;
        _Float16 h = (_Float16)a;
        hh[q] = h;
        ll[q] = (_Float16)((a - (float)h) * 2048.0f);
    }
    *(f16x4*)(oh + (size_t)i * 4) = hh;
    *(f16x4*)(ol + (size_t)i * 4) = ll;
}

// ---------- weight prep ----------
struct Prep8 {
    const float* src[8];
    _Float16* dh[8];
    _Float16* dl[8];
    int logK[8];
    int nelem[8];
};

// W [K][256] f32 -> [256][K] f16 split (8 weights in one launch)
__global__ __launch_bounds__(256) void prep8_kernel(Prep8 p) {
    int y = blockIdx.y;
    int idx = blockIdx.x * 256 + threadIdx.x;
    if (idx >= p.nelem[y]) return;
    int lk = p.logK[y], K = 1 << lk;
    int n = idx >> lk, k = idx & (K - 1);
    float w = p.src[y][(size_t)k * 256 + n];
    _Float16 h = (_Float16)w;
    p.dh[y][(size_t)n * K + k] = h;
    p.dl[y][(size_t)n * K + k] = (_Float16)((w - (float)h) * 2048.0f);
}

// conv1d weight (o, i, t) -> [o][k=t*256+i] split
__global__ __launch_bounds__(256) void prep_conv_kernel(const float* __restrict__ W,
        _Float16* __restrict__ b0, _Float16* __restrict__ b1) {
    int idx = blockIdx.x * 256 + threadIdx.x;  // over 256*1024
    int o = idx >> 10, k = idx & 1023;
    float w = W[(size_t)o * 1024 + (k & 255) * 4 + (k >> 8)];
    _Float16 h = (_Float16)w;
    b0[(size_t)o * 1024 + k] = h;
    b1[(size_t)o * 1024 + k] = (_Float16)((w - (float)h) * 2048.0f);
}

// lin1_w [(c*27+l)][n] -> out [n][k=l*256+c] f16 split, via LDS transpose
__global__ __launch_bounds__(256) void prep_lin1_kernel(const float* __restrict__ l1w,
        _Float16* __restrict__ wh, _Float16* __restrict__ wl_) {
    __shared__ float sh[64][65];
    int kb = blockIdx.x * 64;   // 108 tiles over k
    int nb = blockIdx.y * 64;   // 4 tiles over n
    int t = threadIdx.x;
    {
        int kk = t >> 2;
        int nc = (t & 3) * 16;
        int k = kb + kk, l = k >> 8, c = k & 255;
        const float* srow = l1w + (size_t)(c * 27 + l) * 256 + nb + nc;
        #pragma unroll
        for (int j = 0; j < 16; j += 4) {
            float4 v = *(const float4*)(srow + j);
            sh[kk][nc + j + 0] = v.x;
            sh[kk][nc + j + 1] = v.y;
            sh[kk][nc + j + 2] = v.z;
            sh[kk][nc + j + 3] = v.w;
        }
    }
    __syncthreads();
    {
        int nn = t >> 2;
        int kc = (t & 3) * 16;
        f16x8 oh[2], ol[2];
        #pragma unroll
        for (int j = 0; j < 16; ++j) {
            float x = sh[kc + j][nn];
            _Float16 h = (_Float16)x;
            oh[j >> 3][j & 7] = h;
            ol[j >> 3][j & 7] = (_Float16)((x - (float)h) * 2048.0f);
        }
        size_t o = (size_t)(nb + nn) * 6912 + kb + kc;
        *(f16x8*)(wh + o) = oh[0];
        *(f16x8*)(wh + o + 8) = oh[1];
        *(f16x8*)(wl_ + o) = ol[0];
        *(f16x8*)(wl_ + o + 8) = ol[1];
    }
}

// ---------- per-graph LDS-staged mean aggregation (split IO) ----------
template<int H, int LOGH>
__global__ __launch_bounds__(256) void aggregate_ps_kernel(
        const _Float16* __restrict__ hh, const _Float16* __restrict__ hl,
        const int* __restrict__ offsets, const int* __restrict__ counts,
        const int* __restrict__ ssrc, const float* __restrict__ invdeg,
        _Float16* __restrict__ aggh, _Float16* __restrict__ aggl) {
    __shared__ float sh[64 * H];
    const int g = blockIdx.x, t = threadIdx.x;
    const size_t base = (size_t)g * 64 * H;
    for (int i4 = t * 4; i4 < 64 * H; i4 += 1024) {
        f16x4 vh = *(const f16x4*)(hh + base + i4);
        f16x4 vl = *(const f16x4*)(hl + base + i4);
        int row = i4 >> LOGH, col = i4 & (H - 1);
        int sw = row & 30;
        float x0 = (float)vh[0] + C1F * (float)vl[0];
        float x1 = (float)vh[1] + C1F * (float)vl[1];
        float x2 = (float)vh[2] + C1F * (float)vl[2];
        float x3 = (float)vh[3] + C1F * (float)vl[3];
        *(float2*)&sh[(row << LOGH) + (col ^ sw)] = make_float2(x0, x1);
        *(float2*)&sh[(row << LOGH) + ((col + 2) ^ sw)] = make_float2(x2, x3);
    }
    __syncthreads();
    const int n = t >> 2, fb = t & 3;
    const int FQ = H >> 2;
    const int node = g * 64 + n;
    const int beg = offsets[node], cnt = counts[node];
    float acc[FQ];
    #pragma unroll
    for (int j = 0; j < FQ; ++j) acc[j] = 0.f;
    for (int e = 0; e < cnt; ++e) {
        int sn = ssrc[beg + e] & 63;
        int rowoff = sn << LOGH;
        int sw = sn & 30;
        #pragma unroll
        for (int j = 0; j < FQ; j += 2) {
            int f = fb * FQ + (j ^ (fb * 8));
            float2 v = *(float2*)&sh[rowoff + (f ^ sw)];
            acc[j]     += v.x;
            acc[j + 1] += v.y;
        }
    }
    float s = invdeg[node];
    __syncthreads();
    {
        int rowoff = n << LOGH;
        int sw = n & 30;
        #pragma unroll
        for (int j = 0; j < FQ; j += 2) {
            int f = fb * FQ + (j ^ (fb * 8));
            *(float2*)&sh[rowoff + (f ^ sw)] = make_float2(acc[j] * s, acc[j + 1] * s);
        }
    }
    __syncthreads();
    for (int i4 = t * 4; i4 < 64 * H; i4 += 1024) {
        int row = i4 >> LOGH, col = i4 & (H - 1);
        int sw = row & 30;
        float2 a = *(float2*)&sh[(row << LOGH) + (col ^ sw)];
        float2 b = *(float2*)&sh[(row << LOGH) + ((col + 2) ^ sw)];
        float xs[4] = {a.x, a.y, b.x, b.y};
        f16x4 oh, ol;
        #pragma unroll
        for (int q = 0; q < 4; ++q) {
            _Float16 h = (_Float16)xs[q];
            oh[q] = h;
            ol[q] = (_Float16)((xs[q] - (float)h) * 2048.0f);
        }
        *(f16x4*)(aggh + base + i4) = oh;
        *(f16x4*)(aggl + base + i4) = ol;
    }
}

// ---------- pre-split MFMA GEMM: async DMA staging + single-barrier dbuf ----------
// 128x128 block, 32x32x16 frags, wave tile 64x64. A/B stored as f16 pairs
// (v = hi + lo*2^-11). Staging via global_load_lds (16B/lane, wave-uniform dest);
// per-lane source freedom realizes XOR-swizzled granule layout:
//   granule (row R, k-slot q) at byte R*64 + (q^(R&3))*16  -> frag reads spread
//   over all 8 bank-quads. Double-buffered; DMA(k+1) issued before compute(k);
//   single __syncthreads per iter (vmcnt drain lands after compute).
// acc0: a0b0; acc1: a1b0+a0b1 (x2^-11); acc2: a1b1 (x2^-22, NPROD==4).
// 1D grid: rb=bid%nrb (XCD swizzle), cb=bid/nrb.
// EPI 0: bias+relu, split f16 store. EPI 1: f32 partial at Cpart[z][row][col].
template<int NPROD, int CONV, int NPAIRS, int EPI>
__global__ __launch_bounds__(256, 2) void mfma_ps_kernel(
        const _Float16* __restrict__ A1h, const _Float16* __restrict__ A1l,
        const _Float16* __restrict__ A2h, const _Float16* __restrict__ A2l,
        const _Float16* __restrict__ B1h, const _Float16* __restrict__ B1l,
        const _Float16* __restrict__ B2h, const _Float16* __restrict__ B2l,
        const float* __restrict__ bias,
        _Float16* __restrict__ outh, _Float16* __restrict__ outl,
        float* __restrict__ Cpart,
        int lda, int K, int Nd, int nrb) {
    __shared__ _Float16 As[2][2][128 * 32];   // [buf][term][swizzled 8KB]
    __shared__ _Float16 Bs[2][2][128 * 32];
    const int t = threadIdx.x;
    const int lane = t & 63, wave = t >> 6;
    const int wr = wave & 1, wc = wave >> 1;
    const int bid = blockIdx.x;
    const int rb = bid % nrb, cb = bid / nrb;
    const int row0 = rb * 128, col0 = cb * 128;
    const int l31 = lane & 31, hb = lane >> 5, x3 = l31 & 3;
    // staging lane mapping: granule r16 = lane>>2 (row in 16-row chunk), slot = lane&3
    const int r16 = lane >> 2;
    const int qsrc8 = ((lane & 3) ^ (r16 & 3)) * 8;   // source k-granule (elems)
    size_t aoffj[2], boffj[2];
    #pragma unroll
    for (int j = 0; j < 2; ++j) {
        int ar = row0 + wave * 32 + j * 16 + r16;
        aoffj[j] = CONV ? ((size_t)ar * 256 + (size_t)(ar / 27) * 768)
                        : (size_t)ar * (size_t)lda;
        boffj[j] = (size_t)(col0 + wave * 32 + j * 16 + r16) * (size_t)K;
    }
    // fragment read offsets (f16 elems), k-independent
    int aroff[2], broff[2], slot8[2];
    #pragma unroll
    for (int mi = 0; mi < 2; ++mi) aroff[mi] = (wr * 64 + mi * 32 + l31) * 32;
    #pragma unroll
    for (int ni = 0; ni < 2; ++ni) broff[ni] = (wc * 64 + ni * 32 + l31) * 32;
    #pragma unroll
    for (int h = 0; h < 2; ++h) slot8[h] = ((2 * h + hb) ^ x3) * 8;

    const int KV = NPAIRS * K;
    const int kchunk = KV / gridDim.z;
    const int kv_lo = blockIdx.z * kchunk, kv_hi = kv_lo + kchunk;

    f32x16 acc0[2][2], acc1[2][2], acc2[2][2];
    #pragma unroll
    for (int i = 0; i < 2; ++i)
        #pragma unroll
        for (int j = 0; j < 2; ++j) { acc0[i][j] = 0.f; acc1[i][j] = 0.f; acc2[i][j] = 0.f; }

    auto stage = [&](int kv, int b) {
        int p = (NPAIRS == 2 && kv >= K) ? 1 : 0;
        int k = kv - p * K;
        const _Float16* __restrict__ sAh = p ? A2h : A1h;
        const _Float16* __restrict__ sAl = p ? A2l : A1l;
        const _Float16* __restrict__ sBh = p ? B2h : B1h;
        const _Float16* __restrict__ sBl = p ? B2l : B1l;
        #pragma unroll
        for (int j = 0; j < 2; ++j) {
            int ldsbase = (wave * 32 + j * 16) * 32;   // elems
            size_t ga = aoffj[j] + k + qsrc8;
            size_t gb = boffj[j] + k + qsrc8;
            GLDS(sAh + ga, &As[b][0][ldsbase]);
            GLDS(sAl + ga, &As[b][1][ldsbase]);
            GLDS(sBh + gb, &Bs[b][0][ldsbase]);
            GLDS(sBl + gb, &Bs[b][1][ldsbase]);
        }
    };

    stage(kv_lo, 0);
    __syncthreads();
    int b = 0;
    for (int kv = kv_lo; kv < kv_hi; kv += 32) {
        if (kv + 32 < kv_hi) stage(kv + 32, b ^ 1);
        #pragma unroll
        for (int h = 0; h < 2; ++h) {
            f16x8 af0[2], af1[2], bf0[2], bf1[2];
            #pragma unroll
            for (int mi = 0; mi < 2; ++mi) {
                af0[mi] = *(const f16x8*)&As[b][0][aroff[mi] + slot8[h]];
                af1[mi] = *(const f16x8*)&As[b][1][aroff[mi] + slot8[h]];
            }
            #pragma unroll
            for (int ni = 0; ni < 2; ++ni) {
                bf0[ni] = *(const f16x8*)&Bs[b][0][broff[ni] + slot8[h]];
                bf1[ni] = *(const f16x8*)&Bs[b][1][broff[ni] + slot8[h]];
            }
            #pragma unroll
            for (int mi = 0; mi < 2; ++mi)
                #pragma unroll
                for (int ni = 0; ni < 2; ++ni) {
                    acc0[mi][ni] = __builtin_amdgcn_mfma_f32_32x32x16_f16(af0[mi], bf0[ni], acc0[mi][ni], 0, 0, 0);
                    acc1[mi][ni] = __builtin_amdgcn_mfma_f32_32x32x16_f16(af1[mi], bf0[ni], acc1[mi][ni], 0, 0, 0);
                    acc1[mi][ni] = __builtin_amdgcn_mfma_f32_32x32x16_f16(af0[mi], bf1[ni], acc1[mi][ni], 0, 0, 0);
                    if (NPROD == 4)
                        acc2[mi][ni] = __builtin_amdgcn_mfma_f32_32x32x16_f16(af1[mi], bf1[ni], acc2[mi][ni], 0, 0, 0);
                }
        }
        b ^= 1;
        __syncthreads();   // prefetch DMA landed during compute; reads done before overwrite
    }

    // C/D: col = lane&31, row = (reg&3) + 8*(reg>>2) + 4*(lane>>5)  [m74/m101]
    const int rquad = 4 * hb;
    #pragma unroll
    for (int ni = 0; ni < 2; ++ni) {
        int col = col0 + wc * 64 + ni * 32 + l31;
        float bb = (EPI == 0) ? bias[col] : 0.f;
        #pragma unroll
        for (int mi = 0; mi < 2; ++mi) {
            #pragma unroll
            for (int reg = 0; reg < 16; ++reg) {
                float v = acc0[mi][ni][reg] + C1F * acc1[mi][ni][reg];
                if (NPROD == 4) v += C2F * acc2[mi][ni][reg];
                int row = row0 + wr * 64 + mi * 32 + (reg & 3) + 8 * (reg >> 2) + rquad;
                if (EPI == 0) {
                    v = fmaxf(v + bb, 0.f);
                    _Float16 h = (_Float16)v;
                    size_t o = (size_t)row * Nd + col;
                    outh[o] = h;
                    outl[o] = (_Float16)((v - (float)h) * 2048.0f);
                } else {
                    size_t zb = (size_t)blockIdx.z * (size_t)(nrb * 128) * Nd;
                    Cpart[zb + (size_t)row * Nd + col] = v;
                }
            }
        }
    }
}

// ---------- fused sort-pool + top-k gather ----------
__global__ __launch_bounds__(256) void sortgather_kernel(const _Float16* __restrict__ hh,
        const _Float16* __restrict__ hl, _Float16* __restrict__ th, _Float16* __restrict__ tl) {
    __shared__ float vals[PNODES];
    __shared__ int ord[KTOP];
    int g = blockIdx.x, t = threadIdx.x;
    if (t < PNODES) {
        size_t idx = (size_t)(g * PNODES + t) * HID + (HID - 1);
        vals[t] = (float)hh[idx] + C1F * (float)hl[idx];
    }
    __syncthreads();
    if (t < PNODES) {
        float v = vals[t];
        int rank = 0;
        for (int j = 0; j < PNODES; ++j) {
            float vj = vals[j];
            rank += (vj > v) || (vj == v && j < t);
        }
        if (rank < KTOP) ord[rank] = g * PNODES + t;
    }
    __syncthreads();
    for (int r = 0; r < KTOP; ++r) {
        size_t s = (size_t)ord[r] * HID + t;
        size_t d = (size_t)(g * KTOP + r) * HID + t;
        th[d] = hh[s];
        tl[d] = hl[s];
    }
}

// ---------- lin1 reduce (27 partials) ----------
__global__ void reduce_lin1_kernel(const float* __restrict__ z1p,
        const float* __restrict__ b, float* __restrict__ z1) {
    int i = blockIdx.x * 256 + threadIdx.x;   // 131072
    float s = b[i & 255];
    #pragma unroll
    for (int z = 0; z < 27; ++z) s += z1p[(size_t)z * 131072 + i];
    z1[i] = fmaxf(s, 0.f);
}

// ---------- f32 64x64 GEMM (lin2 only) ----------
__global__ __launch_bounds__(256) void gemm64_kernel(
        const float* __restrict__ A, const float* __restrict__ B,
        const float* __restrict__ bias, float* __restrict__ C,
        int lda, int kend, int Nd) {
    __shared__ float As[16][64];
    __shared__ float Bs[16][64];
    const int tid = threadIdx.x;
    const int tx = tid & 15, ty = tid >> 4;
    const int la_r = tid >> 2, la_c = (tid & 3) << 2;
    const int lb_r = tid >> 4, lb_c = (tid & 15) << 2;
    const int row0 = blockIdx.x * 64, col0 = blockIdx.y * 64;
    const size_t aoff = (size_t)(row0 + la_r) * (size_t)lda;
    float acc[4][4] = {};
    for (int k0 = 0; k0 < kend; k0 += 16) {
        __syncthreads();
        float4 av = *(const float4*)(A + aoff + k0 + la_c);
        As[la_c + 0][la_r] = av.x;
        As[la_c + 1][la_r] = av.y;
        As[la_c + 2][la_r] = av.z;
        As[la_c + 3][la_r] = av.w;
        *(float4*)&Bs[lb_r][lb_c] = *(const float4*)(B + (size_t)(k0 + lb_r) * Nd + col0 + lb_c);
        __syncthreads();
        #pragma unroll
        for (int k = 0; k < 16; ++k) {
            float4 a = *(const float4*)&As[k][ty << 2];
            float4 b = *(const float4*)&Bs[k][tx << 2];
            acc[0][0] += a.x * b.x; acc[0][1] += a.x * b.y; acc[0][2] += a.x * b.z; acc[0][3] += a.x * b.w;
            acc[1][0] += a.y * b.x; acc[1][1] += a.y * b.y; acc[1][2] += a.y * b.z; acc[1][3] += a.y * b.w;
            acc[2][0] += a.z * b.x; acc[2][1] += a.z * b.y; acc[2][2] += a.z * b.z; acc[2][3] += a.z * b.w;
            acc[3][0] += a.w * b.x; acc[3][1] += a.w * b.y; acc[3][2] += a.w * b.z; acc[3][3] += a.w * b.w;
        }
    }
    #pragma unroll
    for (int i = 0; i < 4; ++i) {
        int row = row0 + (ty << 2) + i;
        #pragma unroll
        for (int j = 0; j < 4; ++j) {
            int col = col0 + (tx << 2) + j;
            C[(size_t)row * Nd + col] = fmaxf(acc[i][j] + bias[col], 0.f);
        }
    }
}

__global__ void out_kernel(const float* __restrict__ z2, const float* __restrict__ w,
        const float* __restrict__ b, float* __restrict__ out) {
    int idx = blockIdx.x * blockDim.x + threadIdx.x;
    if (idx < NGRAPH * 10) {
        int r = idx / 10, c = idx % 10;
        float s = b[c];
        for (int k = 0; k < 128; ++k) s += z2[r * 128 + k] * w[k * 10 + c];
        out[idx] = fmaxf(s, 0.f);
    }
}

extern "C" void kernel_launch(void* const* d_in, const int* in_sizes, int n_in,
                              void* d_out, int out_size, void* d_ws, size_t ws_size,
                              hipStream_t stream) {
    const float* x    = (const float*)d_in[0];
    const int*   edge = (const int*)d_in[1];
    const int*   esrc = edge;
    const int*   edst = edge + NEDGES;
    const float* wl[4] = {(const float*)d_in[3], (const float*)d_in[6], (const float*)d_in[9],  (const float*)d_in[12]};
    const float* wr[4] = {(const float*)d_in[4], (const float*)d_in[7], (const float*)d_in[10], (const float*)d_in[13]};
    const float* sb[4] = {(const float*)d_in[5], (const float*)d_in[8], (const float*)d_in[11], (const float*)d_in[14]};
    const float* convw = (const float*)d_in[15];
    const float* convb = (const float*)d_in[16];
    const float* l1w   = (const float*)d_in[17];
    const float* l1b   = (const float*)d_in[18];
    const float* l2w   = (const float*)d_in[19];
    const float* l2b   = (const float*)d_in[20];
    const float* ow    = (const float*)d_in[21];
    const float* ob    = (const float*)d_in[22];
    float* out = (float*)d_out;

    char* ws = (char*)d_ws;
    size_t off = 0;
    auto alloc = [&](size_t bytes) -> char* {
        char* p = ws + off;
        off = (off + bytes + 255) & ~(size_t)255;
        return p;
    };
    int*   counts  = (int*)alloc((size_t)NNODES * 4);
    int*   offsets = (int*)alloc((size_t)NNODES * 4);
    int*   cursor  = (int*)alloc((size_t)NNODES * 4);
    int*   loc     = (int*)alloc((size_t)NNODES * 4);
    int*   partial = (int*)alloc(32 * 4);
    float* invdeg  = (float*)alloc((size_t)NNODES * 4);
    int*   ssrc    = (int*)alloc((size_t)NEDGES * 4);
    _Float16* wlh[4]; _Float16* wll[4]; _Float16* wrh[4]; _Float16* wrl[4];
    for (int l = 0; l < 4; ++l) {
        size_t kb = (size_t)(l ? HID : FIN) * HID * 2;
        wlh[l] = (_Float16*)alloc(kb); wll[l] = (_Float16*)alloc(kb);
        wrh[l] = (_Float16*)alloc(kb); wrl[l] = (_Float16*)alloc(kb);
    }
    _Float16* cvh = (_Float16*)alloc((size_t)HID * 1024 * 2);
    _Float16* cvl = (_Float16*)alloc((size_t)HID * 1024 * 2);

    const size_t H0T = (size_t)NNODES * FIN * 2;        // 8.39 MB
    const size_t AGT = (size_t)NNODES * HID * 2;        // 16.78 MB
    const size_t TKT = (size_t)NGRAPH * KTOP * HID * 2; // 7.86 MB
    const size_t YBT = (size_t)NGRAPH * LOUT * HID * 2; // 7.08 MB
    const size_t Z1PT = (size_t)27 * NGRAPH * HID * 4;  // 14.16 MB
    const size_t W1T = (size_t)HID * 6912 * 2;          // 3.54 MB

    char* R1 = alloc(2 * H0T);
    char* R2 = alloc(2 * AGT);
    char* R3 = alloc(2 * AGT);
    char* R4 = alloc(2 * AGT);
    // region 1: h0 split (SAGE phase) -> topk split (tail phase)
    _Float16* h0h = (_Float16*)R1; _Float16* h0l = (_Float16*)(R1 + H0T);
    _Float16* tkh = (_Float16*)R1; _Float16* tkl = (_Float16*)(R1 + TKT);
    // region 2: agg split -> ybl split + z1p + z1 + z2
    _Float16* aggh = (_Float16*)R2; _Float16* aggl = (_Float16*)(R2 + AGT);
    _Float16* ybh = (_Float16*)R2; _Float16* ybl_ = (_Float16*)(R2 + YBT);
    float* z1p = (float*)(R2 + 2 * YBT);
    float* z1  = (float*)(R2 + 2 * YBT + Z1PT);
    float* z2  = (float*)(R2 + 2 * YBT + Z1PT + (size_t)NGRAPH * HID * 4);
    // region 3: hA split -> lin1 weight split
    _Float16* hAh = (_Float16*)R3; _Float16* hAl = (_Float16*)(R3 + AGT);
    _Float16* w1h = (_Float16*)R3; _Float16* w1l = (_Float16*)(R3 + W1T);
    // region 4: hB split (= h4, live to end)
    _Float16* hBh = (_Float16*)R4; _Float16* hBl = (_Float16*)(R4 + AGT);

    // ---- edge prep ----
    hipMemsetAsync(counts, 0, (size_t)NNODES * 4, stream);
    hist_kernel<<<NEDGES / 256, 256, 0, stream>>>(edst, counts);
    scan_block_kernel<<<NNODES / 1024, 1024, 0, stream>>>(counts, loc, partial);
    scan_fixup_kernel<<<NNODES / 1024, 1024, 0, stream>>>(loc, partial, counts, offsets, cursor, invdeg);
    scatter_kernel<<<NEDGES / 256, 256, 0, stream>>>(esrc, edst, cursor, ssrc);
    nan2num_split_kernel<<<(NNODES * FIN / 4) / 256, 256, 0, stream>>>(x, h0h, h0l, NNODES * FIN / 4);

    // ---- weight prep ----
    Prep8 p8;
    for (int l = 0; l < 4; ++l) {
        int K = l ? HID : FIN, lk = l ? 8 : 7;
        p8.src[2 * l] = wl[l];     p8.dh[2 * l] = wlh[l];     p8.dl[2 * l] = wll[l];
        p8.src[2 * l + 1] = wr[l]; p8.dh[2 * l + 1] = wrh[l]; p8.dl[2 * l + 1] = wrl[l];
        p8.logK[2 * l] = lk;   p8.nelem[2 * l] = 256 * K;
        p8.logK[2 * l + 1] = lk; p8.nelem[2 * l + 1] = 256 * K;
    }
    prep8_kernel<<<dim3(256, 8), 256, 0, stream>>>(p8);
    prep_conv_kernel<<<(HID * 1024) / 256, 256, 0, stream>>>(convw, cvh, cvl);

    // ---- layer 0 (K=128) ----
    aggregate_ps_kernel<FIN, 7><<<NGRAPH, 256, 0, stream>>>(h0h, h0l, offsets, counts, ssrc, invdeg, aggh, aggl);
    mfma_ps_kernel<4, 0, 2, 0><<<dim3(256 * 2, 1, 1), 256, 0, stream>>>(
        aggh, aggl, h0h, h0l, wlh[0], wll[0], wrh[0], wrl[0], sb[0], hAh, hAl, nullptr, FIN, FIN, HID, 256);
    // ---- layers 1..3 (K=256) ----
    _Float16* hinh = hAh; _Float16* hinl = hAl;
    _Float16* hoth = hBh; _Float16* hotl = hBl;
    for (int l = 1; l < 4; ++l) {
        aggregate_ps_kernel<HID, 8><<<NGRAPH, 256, 0, stream>>>(hinh, hinl, offsets, counts, ssrc, invdeg, aggh, aggl);
        mfma_ps_kernel<4, 0, 2, 0><<<dim3(256 * 2, 1, 1), 256, 0, stream>>>(
            aggh, aggl, hinh, hinl, wlh[l], wll[l], wrh[l], wrl[l], sb[l], hoth, hotl, nullptr, HID, HID, HID, 256);
        _Float16* t1 = hinh; hinh = hoth; hoth = t1;
        _Float16* t2 = hinl; hinl = hotl; hotl = t2;
    }
    // h4 = (hinh, hinl) = hB region

    sortgather_kernel<<<NGRAPH, 256, 0, stream>>>(hinh, hinl, tkh, tkl);
    prep_lin1_kernel<<<dim3(108, 4), 256, 0, stream>>>(l1w, w1h, w1l);

    // ---- conv1d as GEMM: M=13824, K=1024 ----
    mfma_ps_kernel<3, 1, 1, 0><<<dim3(108 * 2, 1, 1), 256, 0, stream>>>(
        tkh, tkl, nullptr, nullptr, cvh, cvl, nullptr, nullptr, convb, ybh, ybl_, nullptr, 256, 1024, HID, 108);

    // ---- lin1: M=512, K=6912, split-K=27 partials + reduce ----
    mfma_ps_kernel<3, 0, 1, 1><<<dim3(4 * 2, 1, 27), 256, 0, stream>>>(
        ybh, ybl_, nullptr, nullptr, w1h, w1l, nullptr, nullptr, nullptr, nullptr, nullptr, z1p, 6912, 6912, HID, 4);
    reduce_lin1_kernel<<<NGRAPH * HID / 256, 256, 0, stream>>>(z1p, l1b, z1);

    // ---- lin2: M=512, K=256, N=128 ----
    gemm64_kernel<<<dim3(NGRAPH / 64, 128 / 64), 256, 0, stream>>>(z1, l2w, l2b, z2, HID, HID, 128);

    // ---- out ----
    out_kernel<<<(NGRAPH * 10 + 255) / 256, 256, 0, stream>>>(z2, ow, ob, out);
}

// Round 10
// 495.352 us; speedup vs baseline: 1.1449x; 1.0753x over previous
//
#include <hip/hip_runtime.h>
#include <hip/hip_bf16.h>

#define NNODES 32768
#define NEDGES 524288
#define NGRAPH 512
#define PNODES 64
#define KTOP 30
#define FIN 128
#define HID 256
#define LOUT 27

#define C1F 4.8828125e-4f           // 2^-11
#define C2F 2.384185791015625e-7f   // 2^-22

using f16x8 = __attribute__((ext_vector_type(8))) _Float16;
using f16x4 = __attribute__((ext_vector_type(4))) _Float16;
using f32x4 = __attribute__((ext_vector_type(4))) float;
using f32x16 = __attribute__((ext_vector_type(16))) float;

// async global->LDS DMA, 16B per lane, dest = wave-uniform base + lane*16
#define GLDS(src, dst) __builtin_amdgcn_global_load_lds( \
    (const __attribute__((address_space(1))) void*)(src), \
    (__attribute__((address_space(3))) void*)(dst), 16, 0, 0)

// ---------- edge preprocessing ----------
__global__ void hist_kernel(const int* __restrict__ dst, int* __restrict__ counts) {
    int e = blockIdx.x * blockDim.x + threadIdx.x;
    if (e < NEDGES) atomicAdd(&counts[dst[e]], 1);
}

__global__ __launch_bounds__(1024) void scan_block_kernel(const int* __restrict__ counts,
        int* __restrict__ loc, int* __restrict__ partial) {
    int b = blockIdx.x, t = threadIdx.x;
    int i = b * 1024 + t;
    int v = counts[i];
    int lane = t & 63, w = t >> 6;
    int x = v;
    #pragma unroll
    for (int d = 1; d < 64; d <<= 1) { int y = __shfl_up(x, d, 64); if (lane >= d) x += y; }
    __shared__ int ws[16];
    if (lane == 63) ws[w] = x;
    __syncthreads();
    if (w == 0) {
        int s = (lane < 16) ? ws[lane] : 0;
        #pragma unroll
        for (int d = 1; d < 16; d <<= 1) { int y = __shfl_up(s, d, 64); if (lane >= d) s += y; }
        if (lane < 16) ws[lane] = s;
    }
    __syncthreads();
    int base = (w > 0) ? ws[w - 1] : 0;
    int incl = base + x;
    loc[i] = incl - v;
    if (t == 1023) partial[b] = incl;
}

__global__ __launch_bounds__(1024) void scan_fixup_kernel(const int* __restrict__ loc,
        const int* __restrict__ partial, const int* __restrict__ counts,
        int* __restrict__ offsets, int* __restrict__ cursor, float* __restrict__ invdeg) {
    int b = blockIdx.x, t = threadIdx.x;
    int i = b * 1024 + t;
    __shared__ int sbase;
    if (t == 0) { int s = 0; for (int j = 0; j < b; ++j) s += partial[j]; sbase = s; }
    __syncthreads();
    int o = loc[i] + sbase;
    offsets[i] = o;
    cursor[i] = o;
    invdeg[i] = 1.0f / fmaxf((float)counts[i], 1.0f);
}

__global__ void scatter_kernel(const int* __restrict__ src, const int* __restrict__ dst,
        int* __restrict__ cursor, int* __restrict__ ssrc) {
    int e = blockIdx.x * blockDim.x + threadIdx.x;
    if (e < NEDGES) {
        int d = dst[e];
        int p = atomicAdd(&cursor[d], 1);
        ssrc[p] = src[e];
    }
}

// nan_to_num + split to f16 pair
__global__ void nan2num_split_kernel(const float* __restrict__ x,
        _Float16* __restrict__ oh, _Float16* __restrict__ ol, int n4) {
    int i = blockIdx.x * blockDim.x + threadIdx.x;
    if (i >= n4) return;
    float4 v = *(const float4*)(x + i * 4);
    float xs[4] = {v.x, v.y, v.z, v.w};
    f16x4 hh, ll;
    #pragma unroll
    for (int q = 0; q < 4; ++q) {
        float a = xs[q];
        a = (a != a) ? 0.f : a;
        _Float16 h = (_Float16)a;
        hh[q] = h;
        ll[q] = (_Float16)((a - (float)h) * 2048.0f);
    }
    *(f16x4*)(oh + (size_t)i * 4) = hh;
    *(f16x4*)(ol + (size_t)i * 4) = ll;
}

// ---------- weight prep ----------
struct Prep8 {
    const float* src[8];
    _Float16* dh[8];
    _Float16* dl[8];
    int logK[8];
    int nelem[8];
};

// W [K][256] f32 -> [256][K] f16 split (8 weights in one launch)
__global__ __launch_bounds__(256) void prep8_kernel(Prep8 p) {
    int y = blockIdx.y;
    int idx = blockIdx.x * 256 + threadIdx.x;
    if (idx >= p.nelem[y]) return;
    int lk = p.logK[y], K = 1 << lk;
    int n = idx >> lk, k = idx & (K - 1);
    float w = p.src[y][(size_t)k * 256 + n];
    _Float16 h = (_Float16)w;
    p.dh[y][(size_t)n * K + k] = h;
    p.dl[y][(size_t)n * K + k] = (_Float16)((w - (float)h) * 2048.0f);
}

// conv1d weight (o, i, t) -> [o][k=t*256+i] split
__global__ __launch_bounds__(256) void prep_conv_kernel(const float* __restrict__ W,
        _Float16* __restrict__ b0, _Float16* __restrict__ b1) {
    int idx = blockIdx.x * 256 + threadIdx.x;  // over 256*1024
    int o = idx >> 10, k = idx & 1023;
    float w = W[(size_t)o * 1024 + (k & 255) * 4 + (k >> 8)];
    _Float16 h = (_Float16)w;
    b0[(size_t)o * 1024 + k] = h;
    b1[(size_t)o * 1024 + k] = (_Float16)((w - (float)h) * 2048.0f);
}

// lin1_w [(c*27+l)][n] -> out [n][k=l*256+c] f16 split, via LDS transpose
__global__ __launch_bounds__(256) void prep_lin1_kernel(const float* __restrict__ l1w,
        _Float16* __restrict__ wh, _Float16* __restrict__ wl_) {
    __shared__ float sh[64][65];
    int kb = blockIdx.x * 64;   // 108 tiles over k
    int nb = blockIdx.y * 64;   // 4 tiles over n
    int t = threadIdx.x;
    {
        int kk = t >> 2;
        int nc = (t & 3) * 16;
        int k = kb + kk, l = k >> 8, c = k & 255;
        const float* srow = l1w + (size_t)(c * 27 + l) * 256 + nb + nc;
        #pragma unroll
        for (int j = 0; j < 16; j += 4) {
            float4 v = *(const float4*)(srow + j);
            sh[kk][nc + j + 0] = v.x;
            sh[kk][nc + j + 1] = v.y;
            sh[kk][nc + j + 2] = v.z;
            sh[kk][nc + j + 3] = v.w;
        }
    }
    __syncthreads();
    {
        int nn = t >> 2;
        int kc = (t & 3) * 16;
        f16x8 oh[2], ol[2];
        #pragma unroll
        for (int j = 0; j < 16; ++j) {
            float x = sh[kc + j][nn];
            _Float16 h = (_Float16)x;
            oh[j >> 3][j & 7] = h;
            ol[j >> 3][j & 7] = (_Float16)((x - (float)h) * 2048.0f);
        }
        size_t o = (size_t)(nb + nn) * 6912 + kb + kc;
        *(f16x8*)(wh + o) = oh[0];
        *(f16x8*)(wh + o + 8) = oh[1];
        *(f16x8*)(wl_ + o) = ol[0];
        *(f16x8*)(wl_ + o + 8) = ol[1];
    }
}

// ---------- per-graph LDS-staged mean aggregation (split IO, float4 path) ----------
// Swizzle sw = row & 28 keeps all LDS accesses 16B-aligned while spreading
// bank-quads across rows (3 bits of entropy -> 8 quads).
template<int H, int LOGH>
__global__ __launch_bounds__(256) void aggregate_ps_kernel(
        const _Float16* __restrict__ hh, const _Float16* __restrict__ hl,
        const int* __restrict__ offsets, const int* __restrict__ counts,
        const int* __restrict__ ssrc, const float* __restrict__ invdeg,
        _Float16* __restrict__ aggh, _Float16* __restrict__ aggl) {
    __shared__ float sh[64 * H];
    const int g = blockIdx.x, t = threadIdx.x;
    const size_t base = (size_t)g * 64 * H;
    for (int i4 = t * 4; i4 < 64 * H; i4 += 1024) {
        f16x4 vh = *(const f16x4*)(hh + base + i4);
        f16x4 vl = *(const f16x4*)(hl + base + i4);
        int row = i4 >> LOGH, col = i4 & (H - 1);
        int sw = row & 28;
        float4 v = make_float4(
            (float)vh[0] + C1F * (float)vl[0],
            (float)vh[1] + C1F * (float)vl[1],
            (float)vh[2] + C1F * (float)vl[2],
            (float)vh[3] + C1F * (float)vl[3]);
        *(float4*)&sh[(row << LOGH) + (col ^ sw)] = v;
    }
    __syncthreads();
    const int n = t >> 2, fb = t & 3;
    const int FQ = H >> 2;
    const int node = g * 64 + n;
    const int beg = offsets[node], cnt = counts[node];
    float acc[FQ];
    #pragma unroll
    for (int j = 0; j < FQ; ++j) acc[j] = 0.f;
    for (int e = 0; e < cnt; ++e) {
        int sn = ssrc[beg + e] & 63;
        int rowoff = sn << LOGH;
        int sw = sn & 28;
        #pragma unroll
        for (int j = 0; j < FQ; j += 4) {
            int f = fb * FQ + (j ^ (fb * 8));
            float4 v = *(float4*)&sh[rowoff + (f ^ sw)];
            acc[j]     += v.x;
            acc[j + 1] += v.y;
            acc[j + 2] += v.z;
            acc[j + 3] += v.w;
        }
    }
    float s = invdeg[node];
    __syncthreads();
    {
        int rowoff = n << LOGH;
        int sw = n & 28;
        #pragma unroll
        for (int j = 0; j < FQ; j += 4) {
            int f = fb * FQ + (j ^ (fb * 8));
            *(float4*)&sh[rowoff + (f ^ sw)] =
                make_float4(acc[j] * s, acc[j + 1] * s, acc[j + 2] * s, acc[j + 3] * s);
        }
    }
    __syncthreads();
    for (int i4 = t * 4; i4 < 64 * H; i4 += 1024) {
        int row = i4 >> LOGH, col = i4 & (H - 1);
        int sw = row & 28;
        float4 v = *(float4*)&sh[(row << LOGH) + (col ^ sw)];
        float xs[4] = {v.x, v.y, v.z, v.w};
        f16x4 oh, ol;
        #pragma unroll
        for (int q = 0; q < 4; ++q) {
            _Float16 h = (_Float16)xs[q];
            oh[q] = h;
            ol[q] = (_Float16)((xs[q] - (float)h) * 2048.0f);
        }
        *(f16x4*)(aggh + base + i4) = oh;
        *(f16x4*)(aggl + base + i4) = ol;
    }
}

// ---------- pre-split MFMA GEMM: async DMA staging + single-barrier dbuf ----------
// 128x128 block, 32x32x16 frags, wave tile 64x64. A/B stored as f16 pairs
// (v = hi + lo*2^-11). Staging via global_load_lds (16B/lane); XOR-swizzled
// granule layout spreads frag reads over all 8 bank-quads. Double-buffered;
// DMA(k+1) issued before compute(k); single __syncthreads per iter.
// acc0: a0b0; acc1: a1b0+a0b1 (x2^-11); acc2: a1b1 (x2^-22, NPROD==4).
// 1D grid: rb=bid%nrb (XCD swizzle), cb=bid/nrb.
// EPI 0: bias+relu, split f16 store. EPI 1: f32 partial at Cpart[z][row][col].
template<int NPROD, int CONV, int NPAIRS, int EPI>
__global__ __launch_bounds__(256, 2) void mfma_ps_kernel(
        const _Float16* __restrict__ A1h, const _Float16* __restrict__ A1l,
        const _Float16* __restrict__ A2h, const _Float16* __restrict__ A2l,
        const _Float16* __restrict__ B1h, const _Float16* __restrict__ B1l,
        const _Float16* __restrict__ B2h, const _Float16* __restrict__ B2l,
        const float* __restrict__ bias,
        _Float16* __restrict__ outh, _Float16* __restrict__ outl,
        float* __restrict__ Cpart,
        int lda, int K, int Nd, int nrb) {
    __shared__ _Float16 As[2][2][128 * 32];   // [buf][term][swizzled 8KB]
    __shared__ _Float16 Bs[2][2][128 * 32];
    const int t = threadIdx.x;
    const int lane = t & 63, wave = t >> 6;
    const int wr = wave & 1, wc = wave >> 1;
    const int bid = blockIdx.x;
    const int rb = bid % nrb, cb = bid / nrb;
    const int row0 = rb * 128, col0 = cb * 128;
    const int l31 = lane & 31, hb = lane >> 5, x3 = l31 & 3;
    const int r16 = lane >> 2;
    const int qsrc8 = ((lane & 3) ^ (r16 & 3)) * 8;   // source k-granule (elems)
    size_t aoffj[2], boffj[2];
    #pragma unroll
    for (int j = 0; j < 2; ++j) {
        int ar = row0 + wave * 32 + j * 16 + r16;
        aoffj[j] = CONV ? ((size_t)ar * 256 + (size_t)(ar / 27) * 768)
                        : (size_t)ar * (size_t)lda;
        boffj[j] = (size_t)(col0 + wave * 32 + j * 16 + r16) * (size_t)K;
    }
    int aroff[2], broff[2], slot8[2];
    #pragma unroll
    for (int mi = 0; mi < 2; ++mi) aroff[mi] = (wr * 64 + mi * 32 + l31) * 32;
    #pragma unroll
    for (int ni = 0; ni < 2; ++ni) broff[ni] = (wc * 64 + ni * 32 + l31) * 32;
    #pragma unroll
    for (int h = 0; h < 2; ++h) slot8[h] = ((2 * h + hb) ^ x3) * 8;

    const int KV = NPAIRS * K;
    const int kchunk = KV / gridDim.z;
    const int kv_lo = blockIdx.z * kchunk, kv_hi = kv_lo + kchunk;

    f32x16 acc0[2][2], acc1[2][2], acc2[2][2];
    #pragma unroll
    for (int i = 0; i < 2; ++i)
        #pragma unroll
        for (int j = 0; j < 2; ++j) { acc0[i][j] = 0.f; acc1[i][j] = 0.f; acc2[i][j] = 0.f; }

    auto stage = [&](int kv, int b) {
        int p = (NPAIRS == 2 && kv >= K) ? 1 : 0;
        int k = kv - p * K;
        const _Float16* __restrict__ sAh = p ? A2h : A1h;
        const _Float16* __restrict__ sAl = p ? A2l : A1l;
        const _Float16* __restrict__ sBh = p ? B2h : B1h;
        const _Float16* __restrict__ sBl = p ? B2l : B1l;
        #pragma unroll
        for (int j = 0; j < 2; ++j) {
            int ldsbase = (wave * 32 + j * 16) * 32;   // elems
            size_t ga = aoffj[j] + k + qsrc8;
            size_t gb = boffj[j] + k + qsrc8;
            GLDS(sAh + ga, &As[b][0][ldsbase]);
            GLDS(sAl + ga, &As[b][1][ldsbase]);
            GLDS(sBh + gb, &Bs[b][0][ldsbase]);
            GLDS(sBl + gb, &Bs[b][1][ldsbase]);
        }
    };

    stage(kv_lo, 0);
    __syncthreads();
    int b = 0;
    for (int kv = kv_lo; kv < kv_hi; kv += 32) {
        if (kv + 32 < kv_hi) stage(kv + 32, b ^ 1);
        #pragma unroll
        for (int h = 0; h < 2; ++h) {
            f16x8 af0[2], af1[2], bf0[2], bf1[2];
            #pragma unroll
            for (int mi = 0; mi < 2; ++mi) {
                af0[mi] = *(const f16x8*)&As[b][0][aroff[mi] + slot8[h]];
                af1[mi] = *(const f16x8*)&As[b][1][aroff[mi] + slot8[h]];
            }
            #pragma unroll
            for (int ni = 0; ni < 2; ++ni) {
                bf0[ni] = *(const f16x8*)&Bs[b][0][broff[ni] + slot8[h]];
                bf1[ni] = *(const f16x8*)&Bs[b][1][broff[ni] + slot8[h]];
            }
            #pragma unroll
            for (int mi = 0; mi < 2; ++mi)
                #pragma unroll
                for (int ni = 0; ni < 2; ++ni) {
                    acc0[mi][ni] = __builtin_amdgcn_mfma_f32_32x32x16_f16(af0[mi], bf0[ni], acc0[mi][ni], 0, 0, 0);
                    acc1[mi][ni] = __builtin_amdgcn_mfma_f32_32x32x16_f16(af1[mi], bf0[ni], acc1[mi][ni], 0, 0, 0);
                    acc1[mi][ni] = __builtin_amdgcn_mfma_f32_32x32x16_f16(af0[mi], bf1[ni], acc1[mi][ni], 0, 0, 0);
                    if (NPROD == 4)
                        acc2[mi][ni] = __builtin_amdgcn_mfma_f32_32x32x16_f16(af1[mi], bf1[ni], acc2[mi][ni], 0, 0, 0);
                }
        }
        b ^= 1;
        __syncthreads();   // prefetch DMA landed during compute; reads done before overwrite
    }

    // C/D: col = lane&31, row = (reg&3) + 8*(reg>>2) + 4*(lane>>5)  [m74/m101]
    const int rquad = 4 * hb;
    #pragma unroll
    for (int ni = 0; ni < 2; ++ni) {
        int col = col0 + wc * 64 + ni * 32 + l31;
        float bb = (EPI == 0) ? bias[col] : 0.f;
        #pragma unroll
        for (int mi = 0; mi < 2; ++mi) {
            #pragma unroll
            for (int reg = 0; reg < 16; ++reg) {
                float v = acc0[mi][ni][reg] + C1F * acc1[mi][ni][reg];
                if (NPROD == 4) v += C2F * acc2[mi][ni][reg];
                int row = row0 + wr * 64 + mi * 32 + (reg & 3) + 8 * (reg >> 2) + rquad;
                if (EPI == 0) {
                    v = fmaxf(v + bb, 0.f);
                    _Float16 h = (_Float16)v;
                    size_t o = (size_t)row * Nd + col;
                    outh[o] = h;
                    outl[o] = (_Float16)((v - (float)h) * 2048.0f);
                } else {
                    size_t zb = (size_t)blockIdx.z * (size_t)(nrb * 128) * Nd;
                    Cpart[zb + (size_t)row * Nd + col] = v;
                }
            }
        }
    }
}

// ---------- fused sort-pool + top-k gather ----------
__global__ __launch_bounds__(256) void sortgather_kernel(const _Float16* __restrict__ hh,
        const _Float16* __restrict__ hl, _Float16* __restrict__ th, _Float16* __restrict__ tl) {
    __shared__ float vals[PNODES];
    __shared__ int ord[KTOP];
    int g = blockIdx.x, t = threadIdx.x;
    if (t < PNODES) {
        size_t idx = (size_t)(g * PNODES + t) * HID + (HID - 1);
        vals[t] = (float)hh[idx] + C1F * (float)hl[idx];
    }
    __syncthreads();
    if (t < PNODES) {
        float v = vals[t];
        int rank = 0;
        for (int j = 0; j < PNODES; ++j) {
            float vj = vals[j];
            rank += (vj > v) || (vj == v && j < t);
        }
        if (rank < KTOP) ord[rank] = g * PNODES + t;
    }
    __syncthreads();
    for (int r = 0; r < KTOP; ++r) {
        size_t s = (size_t)ord[r] * HID + t;
        size_t d = (size_t)(g * KTOP + r) * HID + t;
        th[d] = hh[s];
        tl[d] = hl[s];
    }
}

// ---------- conv reduce: sum 2 partials + bias + relu + split ----------
__global__ void reduce_conv_kernel(const float* __restrict__ yb32,
        const float* __restrict__ b, _Float16* __restrict__ ybh, _Float16* __restrict__ ybl) {
    int i = blockIdx.x * 256 + threadIdx.x;   // over 13824*256
    float v = fmaxf(yb32[i] + yb32[i + 13824 * 256] + b[i & 255], 0.f);
    _Float16 h = (_Float16)v;
    ybh[i] = h;
    ybl[i] = (_Float16)((v - (float)h) * 2048.0f);
}

// ---------- lin1 reduce (27 partials) ----------
__global__ void reduce_lin1_kernel(const float* __restrict__ z1p,
        const float* __restrict__ b, float* __restrict__ z1) {
    int i = blockIdx.x * 256 + threadIdx.x;   // 131072
    float s = b[i & 255];
    #pragma unroll
    for (int z = 0; z < 27; ++z) s += z1p[(size_t)z * 131072 + i];
    z1[i] = fmaxf(s, 0.f);
}

// ---------- f32 64x64 GEMM (lin2 only) ----------
__global__ __launch_bounds__(256) void gemm64_kernel(
        const float* __restrict__ A, const float* __restrict__ B,
        const float* __restrict__ bias, float* __restrict__ C,
        int lda, int kend, int Nd) {
    __shared__ float As[16][64];
    __shared__ float Bs[16][64];
    const int tid = threadIdx.x;
    const int tx = tid & 15, ty = tid >> 4;
    const int la_r = tid >> 2, la_c = (tid & 3) << 2;
    const int lb_r = tid >> 4, lb_c = (tid & 15) << 2;
    const int row0 = blockIdx.x * 64, col0 = blockIdx.y * 64;
    const size_t aoff = (size_t)(row0 + la_r) * (size_t)lda;
    float acc[4][4] = {};
    for (int k0 = 0; k0 < kend; k0 += 16) {
        __syncthreads();
        float4 av = *(const float4*)(A + aoff + k0 + la_c);
        As[la_c + 0][la_r] = av.x;
        As[la_c + 1][la_r] = av.y;
        As[la_c + 2][la_r] = av.z;
        As[la_c + 3][la_r] = av.w;
        *(float4*)&Bs[lb_r][lb_c] = *(const float4*)(B + (size_t)(k0 + lb_r) * Nd + col0 + lb_c);
        __syncthreads();
        #pragma unroll
        for (int k = 0; k < 16; ++k) {
            float4 a = *(const float4*)&As[k][ty << 2];
            float4 b = *(const float4*)&Bs[k][tx << 2];
            acc[0][0] += a.x * b.x; acc[0][1] += a.x * b.y; acc[0][2] += a.x * b.z; acc[0][3] += a.x * b.w;
            acc[1][0] += a.y * b.x; acc[1][1] += a.y * b.y; acc[1][2] += a.y * b.z; acc[1][3] += a.y * b.w;
            acc[2][0] += a.z * b.x; acc[2][1] += a.z * b.y; acc[2][2] += a.z * b.z; acc[2][3] += a.z * b.w;
            acc[3][0] += a.w * b.x; acc[3][1] += a.w * b.y; acc[3][2] += a.w * b.z; acc[3][3] += a.w * b.w;
        }
    }
    #pragma unroll
    for (int i = 0; i < 4; ++i) {
        int row = row0 + (ty << 2) + i;
        #pragma unroll
        for (int j = 0; j < 4; ++j) {
            int col = col0 + (tx << 2) + j;
            C[(size_t)row * Nd + col] = fmaxf(acc[i][j] + bias[col], 0.f);
        }
    }
}

__global__ void out_kernel(const float* __restrict__ z2, const float* __restrict__ w,
        const float* __restrict__ b, float* __restrict__ out) {
    int idx = blockIdx.x * blockDim.x + threadIdx.x;
    if (idx < NGRAPH * 10) {
        int r = idx / 10, c = idx % 10;
        float s = b[c];
        for (int k = 0; k < 128; ++k) s += z2[r * 128 + k] * w[k * 10 + c];
        out[idx] = fmaxf(s, 0.f);
    }
}

extern "C" void kernel_launch(void* const* d_in, const int* in_sizes, int n_in,
                              void* d_out, int out_size, void* d_ws, size_t ws_size,
                              hipStream_t stream) {
    const float* x    = (const float*)d_in[0];
    const int*   edge = (const int*)d_in[1];
    const int*   esrc = edge;
    const int*   edst = edge + NEDGES;
    const float* wl[4] = {(const float*)d_in[3], (const float*)d_in[6], (const float*)d_in[9],  (const float*)d_in[12]};
    const float* wr[4] = {(const float*)d_in[4], (const float*)d_in[7], (const float*)d_in[10], (const float*)d_in[13]};
    const float* sb[4] = {(const float*)d_in[5], (const float*)d_in[8], (const float*)d_in[11], (const float*)d_in[14]};
    const float* convw = (const float*)d_in[15];
    const float* convb = (const float*)d_in[16];
    const float* l1w   = (const float*)d_in[17];
    const float* l1b   = (const float*)d_in[18];
    const float* l2w   = (const float*)d_in[19];
    const float* l2b   = (const float*)d_in[20];
    const float* ow    = (const float*)d_in[21];
    const float* ob    = (const float*)d_in[22];
    float* out = (float*)d_out;

    char* ws = (char*)d_ws;
    size_t off = 0;
    auto alloc = [&](size_t bytes) -> char* {
        char* p = ws + off;
        off = (off + bytes + 255) & ~(size_t)255;
        return p;
    };
    int*   counts  = (int*)alloc((size_t)NNODES * 4);
    int*   offsets = (int*)alloc((size_t)NNODES * 4);
    int*   cursor  = (int*)alloc((size_t)NNODES * 4);
    int*   loc     = (int*)alloc((size_t)NNODES * 4);
    int*   partial = (int*)alloc(32 * 4);
    float* invdeg  = (float*)alloc((size_t)NNODES * 4);
    int*   ssrc    = (int*)alloc((size_t)NEDGES * 4);
    _Float16* wlh[4]; _Float16* wll[4]; _Float16* wrh[4]; _Float16* wrl[4];
    for (int l = 0; l < 4; ++l) {
        size_t kb = (size_t)(l ? HID : FIN) * HID * 2;
        wlh[l] = (_Float16*)alloc(kb); wll[l] = (_Float16*)alloc(kb);
        wrh[l] = (_Float16*)alloc(kb); wrl[l] = (_Float16*)alloc(kb);
    }
    _Float16* cvh = (_Float16*)alloc((size_t)HID * 1024 * 2);
    _Float16* cvl = (_Float16*)alloc((size_t)HID * 1024 * 2);

    const size_t H0T = (size_t)NNODES * FIN * 2;        // 8.39 MB
    const size_t AGT = (size_t)NNODES * HID * 2;        // 16.78 MB
    const size_t TKT = (size_t)NGRAPH * KTOP * HID * 2; // 7.86 MB
    const size_t YBT = (size_t)NGRAPH * LOUT * HID * 2; // 7.08 MB
    const size_t YB32T = (size_t)2 * 13824 * 256 * 4;   // 28.3 MB (2 conv partials)
    const size_t Z1PT = (size_t)27 * NGRAPH * HID * 4;  // 14.16 MB
    const size_t W1T = (size_t)HID * 6912 * 2;          // 3.54 MB

    char* R1 = alloc(2 * H0T);
    char* R2 = alloc(2 * AGT);
    char* R3 = alloc(2 * AGT);   // contiguous after R2 (sizes are 256-aligned)
    char* R4 = alloc(2 * AGT);
    // region 1: h0 split (SAGE phase) -> topk split (tail phase)
    _Float16* h0h = (_Float16*)R1; _Float16* h0l = (_Float16*)(R1 + H0T);
    _Float16* tkh = (_Float16*)R1; _Float16* tkl = (_Float16*)(R1 + TKT);
    // region 2+3 (SAGE: agg split in R2, hA split in R3; both dead in tail phase):
    // tail: ybh/ybl | yb32 (union z1p) | z1 | z2 | w1h/w1l  — fits in R2+R3 (67 MB)
    _Float16* aggh = (_Float16*)R2; _Float16* aggl = (_Float16*)(R2 + AGT);
    _Float16* hAh = (_Float16*)R3; _Float16* hAl = (_Float16*)(R3 + AGT);
    _Float16* ybh = (_Float16*)R2; _Float16* ybl_ = (_Float16*)(R2 + YBT);
    float* yb32 = (float*)(R2 + 2 * YBT);
    float* z1p  = (float*)(R2 + 2 * YBT);   // union: yb32 dead before lin1
    char* tail2 = R2 + 2 * YBT + YB32T;
    float* z1  = (float*)tail2;
    float* z2  = (float*)(tail2 + (size_t)NGRAPH * HID * 4);
    _Float16* w1h = (_Float16*)(tail2 + (size_t)NGRAPH * HID * 4 + (size_t)NGRAPH * 128 * 4 + 256);
    _Float16* w1l = (_Float16*)((char*)w1h + W1T);
    // region 4: hB split (= h4, live to end)
    _Float16* hBh = (_Float16*)R4; _Float16* hBl = (_Float16*)(R4 + AGT);

    // ---- edge prep ----
    hipMemsetAsync(counts, 0, (size_t)NNODES * 4, stream);
    hist_kernel<<<NEDGES / 256, 256, 0, stream>>>(edst, counts);
    scan_block_kernel<<<NNODES / 1024, 1024, 0, stream>>>(counts, loc, partial);
    scan_fixup_kernel<<<NNODES / 1024, 1024, 0, stream>>>(loc, partial, counts, offsets, cursor, invdeg);
    scatter_kernel<<<NEDGES / 256, 256, 0, stream>>>(esrc, edst, cursor, ssrc);
    nan2num_split_kernel<<<(NNODES * FIN / 4) / 256, 256, 0, stream>>>(x, h0h, h0l, NNODES * FIN / 4);

    // ---- weight prep ----
    Prep8 p8;
    for (int l = 0; l < 4; ++l) {
        int K = l ? HID : FIN, lk = l ? 8 : 7;
        p8.src[2 * l] = wl[l];     p8.dh[2 * l] = wlh[l];     p8.dl[2 * l] = wll[l];
        p8.src[2 * l + 1] = wr[l]; p8.dh[2 * l + 1] = wrh[l]; p8.dl[2 * l + 1] = wrl[l];
        p8.logK[2 * l] = lk;   p8.nelem[2 * l] = 256 * K;
        p8.logK[2 * l + 1] = lk; p8.nelem[2 * l + 1] = 256 * K;
    }
    prep8_kernel<<<dim3(256, 8), 256, 0, stream>>>(p8);
    prep_conv_kernel<<<(HID * 1024) / 256, 256, 0, stream>>>(convw, cvh, cvl);

    // ---- layer 0 (K=128) ----
    aggregate_ps_kernel<FIN, 7><<<NGRAPH, 256, 0, stream>>>(h0h, h0l, offsets, counts, ssrc, invdeg, aggh, aggl);
    mfma_ps_kernel<3, 0, 2, 0><<<dim3(256 * 2, 1, 1), 256, 0, stream>>>(
        aggh, aggl, h0h, h0l, wlh[0], wll[0], wrh[0], wrl[0], sb[0], hAh, hAl, nullptr, FIN, FIN, HID, 256);
    // ---- layers 1..3 (K=256) ----
    _Float16* hinh = hAh; _Float16* hinl = hAl;
    _Float16* hoth = hBh; _Float16* hotl = hBl;
    for (int l = 1; l < 4; ++l) {
        aggregate_ps_kernel<HID, 8><<<NGRAPH, 256, 0, stream>>>(hinh, hinl, offsets, counts, ssrc, invdeg, aggh, aggl);
        mfma_ps_kernel<3, 0, 2, 0><<<dim3(256 * 2, 1, 1), 256, 0, stream>>>(
            aggh, aggl, hinh, hinl, wlh[l], wll[l], wrh[l], wrl[l], sb[l], hoth, hotl, nullptr, HID, HID, HID, 256);
        _Float16* t1 = hinh; hinh = hoth; hoth = t1;
        _Float16* t2 = hinl; hinl = hotl; hotl = t2;
    }
    // h4 = (hinh, hinl) = hB region; hA + agg dead -> tail phase may reuse R2/R3

    sortgather_kernel<<<NGRAPH, 256, 0, stream>>>(hinh, hinl, tkh, tkl);
    prep_lin1_kernel<<<dim3(108, 4), 256, 0, stream>>>(l1w, w1h, w1l);

    // ---- conv1d as GEMM: M=13824, K=1024, split-K=2 partials + fused reduce ----
    mfma_ps_kernel<3, 1, 1, 1><<<dim3(108 * 2, 1, 2), 256, 0, stream>>>(
        tkh, tkl, nullptr, nullptr, cvh, cvl, nullptr, nullptr, nullptr, nullptr, nullptr, yb32, 256, 1024, HID, 108);
    reduce_conv_kernel<<<13824 * 256 / 256, 256, 0, stream>>>(yb32, convb, ybh, ybl_);

    // ---- lin1: M=512, K=6912, split-K=27 partials + reduce (z1p unions yb32) ----
    mfma_ps_kernel<3, 0, 1, 1><<<dim3(4 * 2, 1, 27), 256, 0, stream>>>(
        ybh, ybl_, nullptr, nullptr, w1h, w1l, nullptr, nullptr, nullptr, nullptr, nullptr, z1p, 6912, 6912, HID, 4);
    reduce_lin1_kernel<<<NGRAPH * HID / 256, 256, 0, stream>>>(z1p, l1b, z1);

    // ---- lin2: M=512, K=256, N=128 ----
    gemm64_kernel<<<dim3(NGRAPH / 64, 128 / 64), 256, 0, stream>>>(z1, l2w, l2b, z2, HID, HID, 128);

    // ---- out ----
    out_kernel<<<(NGRAPH * 10 + 255) / 256, 256, 0, stream>>>(z2, ow, ob, out);
}